// Round 1
// baseline (159.289 us; speedup 1.0000x reference)
//
#include <hip/hip_runtime.h>
#include <math.h>

// Problem constants (match reference)
#define M_PTS 2048
#define N_VOX 65536

// ws float layout:
//   [0,2048)      px  (pred x / RES)
//   [2048,4096)   py
//   [4096,6144)   pz
//   [6144,6148)   accumulators: {pred_sum, fo_sum, mask_occ_sum, mask_sum}

__global__ __launch_bounds__(256) void k_prep(const float* __restrict__ quat,
                                              const float* __restrict__ tran,
                                              const float* __restrict__ model,
                                              const float* __restrict__ view,
                                              float* __restrict__ ws) {
    __shared__ float W[16];
    const int tid = threadIdx.x;

    if (tid == 0) {
        // --- quaternion matrix (mat_eye) ---
        float q0 = quat[0], q1 = quat[1], q2 = quat[2], q3 = quat[3];
        float n = q0*q0 + q1*q1 + q2*q2 + q3*q3;
        float s = sqrtf(2.0f / n);
        q0 *= s; q1 *= s; q2 *= s; q3 *= s;
        float E[16];
        E[0]  = 1.0f - q2*q2 - q3*q3; E[1]  = q1*q2 - q3*q0;       E[2]  = q1*q3 + q2*q0;       E[3]  = tran[0];
        E[4]  = q1*q2 + q3*q0;        E[5]  = 1.0f - q1*q1 - q3*q3; E[6]  = q2*q3 - q1*q0;       E[7]  = tran[1];
        E[8]  = q1*q3 - q2*q0;        E[9]  = q2*q3 + q1*q0;        E[10] = 1.0f - q1*q1 - q2*q2; E[11] = tran[2];
        E[12] = 0.0f; E[13] = 0.0f; E[14] = 0.0f; E[15] = 1.0f;

        // --- 4x4 inverse of view (row-major, MESA cofactor form) ---
        float m[16], inv[16];
        #pragma unroll
        for (int i = 0; i < 16; i++) m[i] = view[i];

        inv[0]  =  m[5]*m[10]*m[15] - m[5]*m[11]*m[14] - m[9]*m[6]*m[15] + m[9]*m[7]*m[14] + m[13]*m[6]*m[11] - m[13]*m[7]*m[10];
        inv[4]  = -m[4]*m[10]*m[15] + m[4]*m[11]*m[14] + m[8]*m[6]*m[15] - m[8]*m[7]*m[14] - m[12]*m[6]*m[11] + m[12]*m[7]*m[10];
        inv[8]  =  m[4]*m[9]*m[15]  - m[4]*m[11]*m[13] - m[8]*m[5]*m[15] + m[8]*m[7]*m[13] + m[12]*m[5]*m[11] - m[12]*m[7]*m[9];
        inv[12] = -m[4]*m[9]*m[14]  + m[4]*m[10]*m[13] + m[8]*m[5]*m[14] - m[8]*m[6]*m[13] - m[12]*m[5]*m[10] + m[12]*m[6]*m[9];
        inv[1]  = -m[1]*m[10]*m[15] + m[1]*m[11]*m[14] + m[9]*m[2]*m[15] - m[9]*m[3]*m[14] - m[13]*m[2]*m[11] + m[13]*m[3]*m[10];
        inv[5]  =  m[0]*m[10]*m[15] - m[0]*m[11]*m[14] - m[8]*m[2]*m[15] + m[8]*m[3]*m[14] + m[12]*m[2]*m[11] - m[12]*m[3]*m[10];
        inv[9]  = -m[0]*m[9]*m[15]  + m[0]*m[11]*m[13] + m[8]*m[1]*m[15] - m[8]*m[3]*m[13] - m[12]*m[1]*m[11] + m[12]*m[3]*m[9];
        inv[13] =  m[0]*m[9]*m[14]  - m[0]*m[10]*m[13] - m[8]*m[1]*m[14] + m[8]*m[2]*m[13] + m[12]*m[1]*m[10] - m[12]*m[2]*m[9];
        inv[2]  =  m[1]*m[6]*m[15]  - m[1]*m[7]*m[14]  - m[5]*m[2]*m[15] + m[5]*m[3]*m[14] + m[13]*m[2]*m[7]  - m[13]*m[3]*m[6];
        inv[6]  = -m[0]*m[6]*m[15]  + m[0]*m[7]*m[14]  + m[4]*m[2]*m[15] - m[4]*m[3]*m[14] - m[12]*m[2]*m[7]  + m[12]*m[3]*m[6];
        inv[10] =  m[0]*m[5]*m[15]  - m[0]*m[7]*m[13]  - m[4]*m[1]*m[15] + m[4]*m[3]*m[13] + m[12]*m[1]*m[7]  - m[12]*m[3]*m[5];
        inv[14] = -m[0]*m[5]*m[14]  + m[0]*m[6]*m[13]  + m[4]*m[1]*m[14] - m[4]*m[2]*m[13] - m[12]*m[1]*m[6]  + m[12]*m[2]*m[5];
        inv[3]  = -m[1]*m[6]*m[11]  + m[1]*m[7]*m[10]  + m[5]*m[2]*m[11] - m[5]*m[3]*m[10] - m[9]*m[2]*m[7]   + m[9]*m[3]*m[6];
        inv[7]  =  m[0]*m[6]*m[11]  - m[0]*m[7]*m[10]  - m[4]*m[2]*m[11] + m[4]*m[3]*m[10] + m[8]*m[2]*m[7]   - m[8]*m[3]*m[6];
        inv[11] = -m[0]*m[5]*m[11]  + m[0]*m[7]*m[9]   + m[4]*m[1]*m[11] - m[4]*m[3]*m[9]  - m[8]*m[1]*m[7]   + m[8]*m[3]*m[5];
        inv[15] =  m[0]*m[5]*m[10]  - m[0]*m[6]*m[9]   - m[4]*m[1]*m[10] + m[4]*m[2]*m[9]  + m[8]*m[1]*m[6]   - m[8]*m[2]*m[5];

        float det = m[0]*inv[0] + m[1]*inv[4] + m[2]*inv[8] + m[3]*inv[12];
        float rdet = 1.0f / det;

        // --- W = inv(view) * E ---
        #pragma unroll
        for (int r = 0; r < 4; r++) {
            #pragma unroll
            for (int c = 0; c < 4; c++) {
                float acc = 0.0f;
                #pragma unroll
                for (int k = 0; k < 4; k++) acc += inv[4*r+k] * rdet * E[4*k+c];
                W[4*r+c] = acc;
            }
        }
    }
    // zero the accumulators (ws is 0xAA-poisoned before every launch)
    if (tid < 4) ws[6144 + tid] = 0.0f;
    __syncthreads();

    // transform the 2048 model points, pre-scale by 1/RES = 2.0
    for (int i = tid; i < M_PTS; i += 256) {
        float x = model[3*i + 0];
        float y = model[3*i + 1];
        float z = model[3*i + 2];
        float X  = W[0]*x + W[1]*y + W[2]*z  + W[3];
        float Y  = W[4]*x + W[5]*y + W[6]*z  + W[7];
        float Z  = W[8]*x + W[9]*y + W[10]*z + W[11];
        float Wd = W[12]*x + W[13]*y + W[14]*z + W[15];
        float rw = 2.0f / Wd;   // (1/w) * (1/RES)
        ws[i]          = X * rw;
        ws[2048 + i]   = Y * rw;
        ws[4096 + i]   = Z * rw;
    }
}

__global__ __launch_bounds__(256) void k_main(const float* __restrict__ centers,
                                              const float* __restrict__ freev,
                                              const float* __restrict__ occ_other,
                                              const float* __restrict__ masks,
                                              const float* __restrict__ ws_pts,
                                              float* __restrict__ acc) {
    __shared__ float s[6144];
    const int tid = threadIdx.x;

    // cooperative stage of all 2048 points (SoA) into LDS via float4
    {
        const float4* src = (const float4*)ws_pts;
        float4* dst = (float4*)s;
        #pragma unroll
        for (int k = 0; k < 6; k++) dst[tid + 256*k] = src[tid + 256*k];
    }
    __syncthreads();

    const int i = blockIdx.x * 256 + tid;
    const float cx = centers[3*i + 0] * 2.0f;   // /RES
    const float cy = centers[3*i + 1] * 2.0f;
    const float cz = centers[3*i + 2] * 2.0f;

    const float4* px = (const float4*)(s);
    const float4* py = (const float4*)(s + 2048);
    const float4* pz = (const float4*)(s + 4096);

    // 4 independent min accumulators (break dependent-min chain; 1 wave/SIMD)
    float m0 = 1e30f, m1 = 1e30f, m2 = 1e30f, m3 = 1e30f;

    #pragma unroll 4
    for (int j = 0; j < M_PTS / 4; j++) {
        float4 ax = px[j];   // wave-uniform address -> LDS broadcast
        float4 ay = py[j];
        float4 az = pz[j];
        float dx, dy, dz, d2;
        dx = cx - ax.x; dy = cy - ay.x; dz = cz - az.x;
        d2 = fmaf(dx, dx, fmaf(dy, dy, dz*dz)); m0 = fminf(m0, d2);
        dx = cx - ax.y; dy = cy - ay.y; dz = cz - az.y;
        d2 = fmaf(dx, dx, fmaf(dy, dy, dz*dz)); m1 = fminf(m1, d2);
        dx = cx - ax.z; dy = cy - ay.z; dz = cz - az.z;
        d2 = fmaf(dx, dx, fmaf(dy, dy, dz*dz)); m2 = fminf(m2, d2);
        dx = cx - ax.w; dy = cy - ay.w; dz = cz - az.w;
        d2 = fmaf(dx, dx, fmaf(dy, dy, dz*dz)); m3 = fminf(m3, d2);
    }
    float md   = fminf(fminf(m0, m1), fminf(m2, m3));
    float dmin = sqrtf(fmaxf(md, 0.0f));
    dmin = fminf(dmin, 0.25f);                       // clamp at RES/2
    float occ = fmaxf(1.0f - dmin * 4.0f, 0.0f);     // 1 - dmin/(RES/2)

    float v0 = occ;
    float v1 = (freev[i] + occ_other[i]) * occ;
    float mk = masks[i];
    float v2 = mk * occ;
    float v3 = mk;

    // wave(64) shuffle reduction
    #pragma unroll
    for (int off = 32; off > 0; off >>= 1) {
        v0 += __shfl_down(v0, off);
        v1 += __shfl_down(v1, off);
        v2 += __shfl_down(v2, off);
        v3 += __shfl_down(v3, off);
    }
    if ((tid & 63) == 0) {
        atomicAdd(&acc[0], v0);
        atomicAdd(&acc[1], v1);
        atomicAdd(&acc[2], v2);
        atomicAdd(&acc[3], v3);
    }
}

__global__ void k_final(const float* __restrict__ acc, float* __restrict__ out) {
    float ps = acc[0], fo = acc[1], mo = acc[2], ms = acc[3];
    float t1 = (ps > 0.0f) ? (fo / ps) : 0.0f;
    float t2 = (ms > 0.0f) ? (mo / ms) : 0.0f;
    out[0] = t1 - t2;
}

extern "C" void kernel_launch(void* const* d_in, const int* in_sizes, int n_in,
                              void* d_out, int out_size, void* d_ws, size_t ws_size,
                              hipStream_t stream) {
    const float* quat      = (const float*)d_in[0];
    const float* tran      = (const float*)d_in[1];
    const float* model     = (const float*)d_in[2];
    const float* view      = (const float*)d_in[3];
    const float* centers   = (const float*)d_in[4];
    const float* freev     = (const float*)d_in[5];
    const float* occ_other = (const float*)d_in[6];
    const float* masks     = (const float*)d_in[7];
    float* out = (float*)d_out;
    float* ws  = (float*)d_ws;

    k_prep<<<1, 256, 0, stream>>>(quat, tran, model, view, ws);
    k_main<<<N_VOX / 256, 256, 0, stream>>>(centers, freev, occ_other, masks, ws, ws + 6144);
    k_final<<<1, 1, 0, stream>>>(ws + 6144, out);
}

// Round 2
// 135.953 us; speedup vs baseline: 1.1716x; 1.1716x over previous
//
#include <hip/hip_runtime.h>
#include <math.h>

#define M_PTS 2048
#define N_VOX 65536
#define VPB   64                 // voxels per block
#define NBLK  (N_VOX / VPB)      // 1024 blocks

// ws layout (floats): [0..3] accumulators {pred_sum, fo_sum, mask_occ_sum, mask_sum}

__global__ __launch_bounds__(256) void k_fused(const float* __restrict__ quat,
                                               const float* __restrict__ tran,
                                               const float* __restrict__ model,
                                               const float* __restrict__ view,
                                               const float* __restrict__ centers,
                                               const float* __restrict__ freev,
                                               const float* __restrict__ occ_other,
                                               const float* __restrict__ masks,
                                               float* __restrict__ acc) {
    __shared__ float4 sp[M_PTS];          // (x,y,z,h)/RES, h = 0.5*|p|^2   -> 32 KB
    __shared__ float  pmin[4 * VPB];      // per-chunk partial mins          -> 1 KB

    const int tid = threadIdx.x;

    // ---- per-block uniform prep: W = inv(view) * quat_matrix (all threads redundantly) ----
    float W[16];
    {
        float q0 = quat[0], q1 = quat[1], q2 = quat[2], q3 = quat[3];
        float nq = q0*q0 + q1*q1 + q2*q2 + q3*q3;
        float s = sqrtf(2.0f / nq);
        q0 *= s; q1 *= s; q2 *= s; q3 *= s;
        float E[16];
        E[0]  = 1.0f - q2*q2 - q3*q3; E[1]  = q1*q2 - q3*q0;        E[2]  = q1*q3 + q2*q0;        E[3]  = tran[0];
        E[4]  = q1*q2 + q3*q0;        E[5]  = 1.0f - q1*q1 - q3*q3; E[6]  = q2*q3 - q1*q0;        E[7]  = tran[1];
        E[8]  = q1*q3 - q2*q0;        E[9]  = q2*q3 + q1*q0;        E[10] = 1.0f - q1*q1 - q2*q2; E[11] = tran[2];
        E[12] = 0.0f; E[13] = 0.0f; E[14] = 0.0f; E[15] = 1.0f;

        float m[16], inv[16];
        #pragma unroll
        for (int i = 0; i < 16; i++) m[i] = view[i];

        inv[0]  =  m[5]*m[10]*m[15] - m[5]*m[11]*m[14] - m[9]*m[6]*m[15] + m[9]*m[7]*m[14] + m[13]*m[6]*m[11] - m[13]*m[7]*m[10];
        inv[4]  = -m[4]*m[10]*m[15] + m[4]*m[11]*m[14] + m[8]*m[6]*m[15] - m[8]*m[7]*m[14] - m[12]*m[6]*m[11] + m[12]*m[7]*m[10];
        inv[8]  =  m[4]*m[9]*m[15]  - m[4]*m[11]*m[13] - m[8]*m[5]*m[15] + m[8]*m[7]*m[13] + m[12]*m[5]*m[11] - m[12]*m[7]*m[9];
        inv[12] = -m[4]*m[9]*m[14]  + m[4]*m[10]*m[13] + m[8]*m[5]*m[14] - m[8]*m[6]*m[13] - m[12]*m[5]*m[10] + m[12]*m[6]*m[9];
        inv[1]  = -m[1]*m[10]*m[15] + m[1]*m[11]*m[14] + m[9]*m[2]*m[15] - m[9]*m[3]*m[14] - m[13]*m[2]*m[11] + m[13]*m[3]*m[10];
        inv[5]  =  m[0]*m[10]*m[15] - m[0]*m[11]*m[14] - m[8]*m[2]*m[15] + m[8]*m[3]*m[14] + m[12]*m[2]*m[11] - m[12]*m[3]*m[10];
        inv[9]  = -m[0]*m[9]*m[15]  + m[0]*m[11]*m[13] + m[8]*m[1]*m[15] - m[8]*m[3]*m[13] - m[12]*m[1]*m[11] + m[12]*m[3]*m[9];
        inv[13] =  m[0]*m[9]*m[14]  - m[0]*m[10]*m[13] - m[8]*m[1]*m[14] + m[8]*m[2]*m[13] + m[12]*m[1]*m[10] - m[12]*m[2]*m[9];
        inv[2]  =  m[1]*m[6]*m[15]  - m[1]*m[7]*m[14]  - m[5]*m[2]*m[15] + m[5]*m[3]*m[14] + m[13]*m[2]*m[7]  - m[13]*m[3]*m[6];
        inv[6]  = -m[0]*m[6]*m[15]  + m[0]*m[7]*m[14]  + m[4]*m[2]*m[15] - m[4]*m[3]*m[14] - m[12]*m[2]*m[7]  + m[12]*m[3]*m[6];
        inv[10] =  m[0]*m[5]*m[15]  - m[0]*m[7]*m[13]  - m[4]*m[1]*m[15] + m[4]*m[3]*m[13] + m[12]*m[1]*m[7]  - m[12]*m[3]*m[5];
        inv[14] = -m[0]*m[5]*m[14]  + m[0]*m[6]*m[13]  + m[4]*m[1]*m[14] - m[4]*m[2]*m[13] - m[12]*m[1]*m[6]  + m[12]*m[2]*m[5];
        inv[3]  = -m[1]*m[6]*m[11]  + m[1]*m[7]*m[10]  + m[5]*m[2]*m[11] - m[5]*m[3]*m[10] - m[9]*m[2]*m[7]   + m[9]*m[3]*m[6];
        inv[7]  =  m[0]*m[6]*m[11]  - m[0]*m[7]*m[10]  - m[4]*m[2]*m[11] + m[4]*m[3]*m[10] + m[8]*m[2]*m[7]   - m[8]*m[3]*m[6];
        inv[11] = -m[0]*m[5]*m[11]  + m[0]*m[7]*m[9]   + m[4]*m[1]*m[11] - m[4]*m[3]*m[9]  - m[8]*m[1]*m[7]   + m[8]*m[3]*m[5];
        inv[15] =  m[0]*m[5]*m[10]  - m[0]*m[6]*m[9]   - m[4]*m[1]*m[10] + m[4]*m[2]*m[9]  + m[8]*m[1]*m[6]   - m[8]*m[2]*m[5];

        float det = m[0]*inv[0] + m[1]*inv[4] + m[2]*inv[8] + m[3]*inv[12];
        float rdet = 1.0f / det;

        #pragma unroll
        for (int r = 0; r < 4; r++) {
            #pragma unroll
            for (int c = 0; c < 4; c++) {
                float a = 0.0f;
                #pragma unroll
                for (int k = 0; k < 4; k++) a += inv[4*r+k] * rdet * E[4*k+c];
                W[4*r+c] = a;
            }
        }
    }

    // ---- transform model points into LDS: (x,y,z)/RES and h = 0.5*|p|^2 ----
    #pragma unroll
    for (int i = tid; i < M_PTS; i += 256) {
        float x = model[3*i + 0];
        float y = model[3*i + 1];
        float z = model[3*i + 2];
        float X  = W[0]*x + W[1]*y + W[2]*z  + W[3];
        float Y  = W[4]*x + W[5]*y + W[6]*z  + W[7];
        float Z  = W[8]*x + W[9]*y + W[10]*z + W[11];
        float Wd = W[12]*x + W[13]*y + W[14]*z + W[15];
        float rw = 2.0f / Wd;                 // (1/w) * (1/RES)
        float px = X * rw, py = Y * rw, pz = Z * rw;
        float h  = 0.5f * (px*px + py*py + pz*pz);
        sp[i] = make_float4(px, py, pz, h);
    }
    __syncthreads();

    // ---- main: each wave covers a 512-point chunk for 64 voxels ----
    const int lv    = tid & 63;        // voxel within block
    const int chunk = tid >> 6;        // wave id = point chunk
    const int gi    = blockIdx.x * VPB + lv;

    const float cx = centers[3*gi + 0] * 2.0f;  // /RES
    const float cy = centers[3*gi + 1] * 2.0f;
    const float cz = centers[3*gi + 2] * 2.0f;
    const float nx = -cx, ny = -cy, nz = -cz;
    const float c2 = cx*cx + cy*cy + cz*cz;

    const float4* base = sp + chunk * 512;
    float m0 = 1e30f, m1 = 1e30f, m2 = 1e30f, m3 = 1e30f;

    #pragma unroll 4
    for (int j = 0; j < 128; ++j) {
        float4 a = base[j];            // wave-uniform addr -> LDS broadcast
        float4 b = base[j + 128];
        float4 c = base[j + 256];
        float4 d = base[j + 384];
        // t = h - c.p  (monotone in d2 = |c|^2 + 2t)
        m0 = fminf(m0, fmaf(nx, a.x, fmaf(ny, a.y, fmaf(nz, a.z, a.w))));
        m1 = fminf(m1, fmaf(nx, b.x, fmaf(ny, b.y, fmaf(nz, b.z, b.w))));
        m2 = fminf(m2, fmaf(nx, c.x, fmaf(ny, c.y, fmaf(nz, c.z, c.w))));
        m3 = fminf(m3, fmaf(nx, d.x, fmaf(ny, d.y, fmaf(nz, d.z, d.w))));
    }
    pmin[chunk * VPB + lv] = fminf(fminf(m0, m1), fminf(m2, m3));
    __syncthreads();

    // ---- epilogue: wave 0 combines chunks, reduces, atomically accumulates ----
    if (tid < VPB) {
        float m = fminf(fminf(pmin[tid], pmin[VPB + tid]),
                        fminf(pmin[2*VPB + tid], pmin[3*VPB + tid]));
        float d2 = fmaf(2.0f, m, c2);
        float dmin = fminf(sqrtf(fmaxf(d2, 0.0f)), 0.25f);   // clamp at RES/2
        float occ = fmaxf(1.0f - 4.0f * dmin, 0.0f);

        float mk = masks[gi];
        float v0 = occ;
        float v1 = (freev[gi] + occ_other[gi]) * occ;
        float v2 = mk * occ;
        float v3 = mk;

        #pragma unroll
        for (int off = 32; off > 0; off >>= 1) {
            v0 += __shfl_down(v0, off);
            v1 += __shfl_down(v1, off);
            v2 += __shfl_down(v2, off);
            v3 += __shfl_down(v3, off);
        }
        if (tid == 0) {
            atomicAdd(&acc[0], v0);
            atomicAdd(&acc[1], v1);
            atomicAdd(&acc[2], v2);
            atomicAdd(&acc[3], v3);
        }
    }
}

__global__ void k_final(const float* __restrict__ acc, float* __restrict__ out) {
    float ps = acc[0], fo = acc[1], mo = acc[2], ms = acc[3];
    float t1 = (ps > 0.0f) ? (fo / ps) : 0.0f;
    float t2 = (ms > 0.0f) ? (mo / ms) : 0.0f;
    out[0] = t1 - t2;
}

extern "C" void kernel_launch(void* const* d_in, const int* in_sizes, int n_in,
                              void* d_out, int out_size, void* d_ws, size_t ws_size,
                              hipStream_t stream) {
    const float* quat      = (const float*)d_in[0];
    const float* tran      = (const float*)d_in[1];
    const float* model     = (const float*)d_in[2];
    const float* view      = (const float*)d_in[3];
    const float* centers   = (const float*)d_in[4];
    const float* freev     = (const float*)d_in[5];
    const float* occ_other = (const float*)d_in[6];
    const float* masks     = (const float*)d_in[7];
    float* out = (float*)d_out;
    float* acc = (float*)d_ws;

    hipMemsetAsync(acc, 0, 4 * sizeof(float), stream);  // zero accumulators (capture-legal memset node)
    k_fused<<<NBLK, 256, 0, stream>>>(quat, tran, model, view, centers, freev,
                                      occ_other, masks, acc);
    k_final<<<1, 1, 0, stream>>>(acc, out);
}

// Round 3
// 94.245 us; speedup vs baseline: 1.6902x; 1.4425x over previous
//
#include <hip/hip_runtime.h>
#include <math.h>

#define M_PTS 2048
#define N_VOX 65536
#define VPT   4                    // voxels per thread (per lane)
#define VPB   256                  // voxels per block (64 lanes * VPT)
#define NBLK  (N_VOX / VPB)        // 256 blocks

// ws layout (floats): [0, 1024) per-block partials {pred_sum, fo_sum, mask_occ_sum, mask_sum} x 256 blocks

__global__ __launch_bounds__(256) void k_fused(const float* __restrict__ quat,
                                               const float* __restrict__ tran,
                                               const float* __restrict__ model,
                                               const float* __restrict__ view,
                                               const float* __restrict__ centers,
                                               const float* __restrict__ freev,
                                               const float* __restrict__ occ_other,
                                               const float* __restrict__ masks,
                                               float* __restrict__ partial) {
    __shared__ float4 sp[M_PTS];        // (x,y,z)/RES, h = 0.5*|p/RES|^2   -> 32 KB
    __shared__ float  pmin[4 * VPB];    // per-wave partial mins [wave][local voxel] -> 4 KB
    __shared__ float  sred[16];         // cross-wave sum combine

    const int tid = threadIdx.x;

    // ---- per-block uniform prep: W = inv(view) * quat_matrix (redundant on all threads) ----
    float W[16];
    {
        float q0 = quat[0], q1 = quat[1], q2 = quat[2], q3 = quat[3];
        float nq = q0*q0 + q1*q1 + q2*q2 + q3*q3;
        float s = sqrtf(2.0f / nq);
        q0 *= s; q1 *= s; q2 *= s; q3 *= s;
        float E[16];
        E[0]  = 1.0f - q2*q2 - q3*q3; E[1]  = q1*q2 - q3*q0;        E[2]  = q1*q3 + q2*q0;        E[3]  = tran[0];
        E[4]  = q1*q2 + q3*q0;        E[5]  = 1.0f - q1*q1 - q3*q3; E[6]  = q2*q3 - q1*q0;        E[7]  = tran[1];
        E[8]  = q1*q3 - q2*q0;        E[9]  = q2*q3 + q1*q0;        E[10] = 1.0f - q1*q1 - q2*q2; E[11] = tran[2];
        E[12] = 0.0f; E[13] = 0.0f; E[14] = 0.0f; E[15] = 1.0f;

        float m[16], inv[16];
        #pragma unroll
        for (int i = 0; i < 16; i++) m[i] = view[i];

        inv[0]  =  m[5]*m[10]*m[15] - m[5]*m[11]*m[14] - m[9]*m[6]*m[15] + m[9]*m[7]*m[14] + m[13]*m[6]*m[11] - m[13]*m[7]*m[10];
        inv[4]  = -m[4]*m[10]*m[15] + m[4]*m[11]*m[14] + m[8]*m[6]*m[15] - m[8]*m[7]*m[14] - m[12]*m[6]*m[11] + m[12]*m[7]*m[10];
        inv[8]  =  m[4]*m[9]*m[15]  - m[4]*m[11]*m[13] - m[8]*m[5]*m[15] + m[8]*m[7]*m[13] + m[12]*m[5]*m[11] - m[12]*m[7]*m[9];
        inv[12] = -m[4]*m[9]*m[14]  + m[4]*m[10]*m[13] + m[8]*m[5]*m[14] - m[8]*m[6]*m[13] - m[12]*m[5]*m[10] + m[12]*m[6]*m[9];
        inv[1]  = -m[1]*m[10]*m[15] + m[1]*m[11]*m[14] + m[9]*m[2]*m[15] - m[9]*m[3]*m[14] - m[13]*m[2]*m[11] + m[13]*m[3]*m[10];
        inv[5]  =  m[0]*m[10]*m[15] - m[0]*m[11]*m[14] - m[8]*m[2]*m[15] + m[8]*m[3]*m[14] + m[12]*m[2]*m[11] - m[12]*m[3]*m[10];
        inv[9]  = -m[0]*m[9]*m[15]  + m[0]*m[11]*m[13] + m[8]*m[1]*m[15] - m[8]*m[3]*m[13] - m[12]*m[1]*m[11] + m[12]*m[3]*m[9];
        inv[13] =  m[0]*m[9]*m[14]  - m[0]*m[10]*m[13] - m[8]*m[1]*m[14] + m[8]*m[2]*m[13] + m[12]*m[1]*m[10] - m[12]*m[2]*m[9];
        inv[2]  =  m[1]*m[6]*m[15]  - m[1]*m[7]*m[14]  - m[5]*m[2]*m[15] + m[5]*m[3]*m[14] + m[13]*m[2]*m[7]  - m[13]*m[3]*m[6];
        inv[6]  = -m[0]*m[6]*m[15]  + m[0]*m[7]*m[14]  + m[4]*m[2]*m[15] - m[4]*m[3]*m[14] - m[12]*m[2]*m[7]  + m[12]*m[3]*m[6];
        inv[10] =  m[0]*m[5]*m[15]  - m[0]*m[7]*m[13]  - m[4]*m[1]*m[15] + m[4]*m[3]*m[13] + m[12]*m[1]*m[7]  - m[12]*m[3]*m[5];
        inv[14] = -m[0]*m[5]*m[14]  + m[0]*m[6]*m[13]  + m[4]*m[1]*m[14] - m[4]*m[2]*m[13] - m[12]*m[1]*m[6]  + m[12]*m[2]*m[5];
        inv[3]  = -m[1]*m[6]*m[11]  + m[1]*m[7]*m[10]  + m[5]*m[2]*m[11] - m[5]*m[3]*m[10] - m[9]*m[2]*m[7]   + m[9]*m[3]*m[6];
        inv[7]  =  m[0]*m[6]*m[11]  - m[0]*m[7]*m[10]  - m[4]*m[2]*m[11] + m[4]*m[3]*m[10] + m[8]*m[2]*m[7]   - m[8]*m[3]*m[6];
        inv[11] = -m[0]*m[5]*m[11]  + m[0]*m[7]*m[9]   + m[4]*m[1]*m[11] - m[4]*m[3]*m[9]  - m[8]*m[1]*m[7]   + m[8]*m[3]*m[5];
        inv[15] =  m[0]*m[5]*m[10]  - m[0]*m[6]*m[9]   - m[4]*m[1]*m[10] + m[4]*m[2]*m[9]  + m[8]*m[1]*m[6]   - m[8]*m[2]*m[5];

        float det = m[0]*inv[0] + m[1]*inv[4] + m[2]*inv[8] + m[3]*inv[12];
        float rdet = 1.0f / det;

        #pragma unroll
        for (int r = 0; r < 4; r++) {
            #pragma unroll
            for (int c = 0; c < 4; c++) {
                float a = 0.0f;
                #pragma unroll
                for (int k = 0; k < 4; k++) a += inv[4*r+k] * rdet * E[4*k+c];
                W[4*r+c] = a;
            }
        }
    }

    // ---- transform model points into LDS: p/RES and h = 0.5*|p/RES|^2 ----
    #pragma unroll
    for (int i = tid; i < M_PTS; i += 256) {
        float x = model[3*i + 0];
        float y = model[3*i + 1];
        float z = model[3*i + 2];
        float X  = W[0]*x + W[1]*y + W[2]*z  + W[3];
        float Y  = W[4]*x + W[5]*y + W[6]*z  + W[7];
        float Z  = W[8]*x + W[9]*y + W[10]*z + W[11];
        float Wd = W[12]*x + W[13]*y + W[14]*z + W[15];
        float rw = 2.0f / Wd;                 // (1/w) * (1/RES)
        float px = X * rw, py = Y * rw, pz = Z * rw;
        float h  = 0.5f * (px*px + py*py + pz*pz);
        sp[i] = make_float4(px, py, pz, h);
    }
    __syncthreads();

    // ---- main: lane handles 4 voxels; each wave sweeps a 512-point chunk ----
    const int lane = tid & 63;
    const int wave = tid >> 6;
    const int vbase = blockIdx.x * VPB + lane * VPT;   // 4 consecutive voxels per lane

    float nx[VPT], ny[VPT], nz[VPT], mm[VPT];
    #pragma unroll
    for (int k = 0; k < VPT; k++) {
        int g = vbase + k;
        nx[k] = -centers[3*g + 0] * 2.0f;   // -(c/RES)
        ny[k] = -centers[3*g + 1] * 2.0f;
        nz[k] = -centers[3*g + 2] * 2.0f;
        mm[k] = 1e30f;
    }

    const float4* base = sp + wave * 512;
    #pragma unroll 4
    for (int j = 0; j < 512; ++j) {
        float4 p = base[j];                 // wave-uniform addr -> LDS broadcast
        // t = h - c.p  (d2 = |c|^2 + 2t, monotone)
        #pragma unroll
        for (int k = 0; k < VPT; k++)
            mm[k] = fminf(mm[k], fmaf(nx[k], p.x, fmaf(ny[k], p.y, fmaf(nz[k], p.z, p.w))));
    }
    #pragma unroll
    for (int k = 0; k < VPT; k++)
        pmin[wave * VPB + lane * VPT + k] = mm[k];
    __syncthreads();

    // ---- epilogue: thread t owns local voxel t ----
    const int g = blockIdx.x * VPB + tid;
    float m = fminf(fminf(pmin[tid], pmin[VPB + tid]),
                    fminf(pmin[2*VPB + tid], pmin[3*VPB + tid]));
    float cx = centers[3*g + 0] * 2.0f;
    float cy = centers[3*g + 1] * 2.0f;
    float cz = centers[3*g + 2] * 2.0f;
    float c2 = cx*cx + cy*cy + cz*cz;
    float d2 = fmaf(2.0f, m, c2);
    float dmin = fminf(sqrtf(fmaxf(d2, 0.0f)), 0.25f);   // clamp at RES/2
    float occ  = fmaxf(1.0f - 4.0f * dmin, 0.0f);

    float mk = masks[g];
    float v0 = occ;
    float v1 = (freev[g] + occ_other[g]) * occ;
    float v2 = mk * occ;
    float v3 = mk;

    #pragma unroll
    for (int off = 32; off > 0; off >>= 1) {
        v0 += __shfl_down(v0, off);
        v1 += __shfl_down(v1, off);
        v2 += __shfl_down(v2, off);
        v3 += __shfl_down(v3, off);
    }
    if (lane == 0) {
        sred[wave*4 + 0] = v0;
        sred[wave*4 + 1] = v1;
        sred[wave*4 + 2] = v2;
        sred[wave*4 + 3] = v3;
    }
    __syncthreads();
    if (tid < 4) {
        float s = sred[tid] + sred[4 + tid] + sred[8 + tid] + sred[12 + tid];
        partial[blockIdx.x * 4 + tid] = s;
    }
}

__global__ __launch_bounds__(256) void k_final(const float* __restrict__ partial,
                                               float* __restrict__ out) {
    __shared__ float sred[16];
    const int tid  = threadIdx.x;
    const int lane = tid & 63;
    const int wave = tid >> 6;

    float4 p = ((const float4*)partial)[tid];   // one block's 4 partials per thread
    float v0 = p.x, v1 = p.y, v2 = p.z, v3 = p.w;

    #pragma unroll
    for (int off = 32; off > 0; off >>= 1) {
        v0 += __shfl_down(v0, off);
        v1 += __shfl_down(v1, off);
        v2 += __shfl_down(v2, off);
        v3 += __shfl_down(v3, off);
    }
    if (lane == 0) {
        sred[wave*4 + 0] = v0;
        sred[wave*4 + 1] = v1;
        sred[wave*4 + 2] = v2;
        sred[wave*4 + 3] = v3;
    }
    __syncthreads();
    if (tid == 0) {
        float ps = sred[0] + sred[4] + sred[8]  + sred[12];
        float fo = sred[1] + sred[5] + sred[9]  + sred[13];
        float mo = sred[2] + sred[6] + sred[10] + sred[14];
        float ms = sred[3] + sred[7] + sred[11] + sred[15];
        float t1 = (ps > 0.0f) ? (fo / ps) : 0.0f;
        float t2 = (ms > 0.0f) ? (mo / ms) : 0.0f;
        out[0] = t1 - t2;
    }
}

extern "C" void kernel_launch(void* const* d_in, const int* in_sizes, int n_in,
                              void* d_out, int out_size, void* d_ws, size_t ws_size,
                              hipStream_t stream) {
    const float* quat      = (const float*)d_in[0];
    const float* tran      = (const float*)d_in[1];
    const float* model     = (const float*)d_in[2];
    const float* view      = (const float*)d_in[3];
    const float* centers   = (const float*)d_in[4];
    const float* freev     = (const float*)d_in[5];
    const float* occ_other = (const float*)d_in[6];
    const float* masks     = (const float*)d_in[7];
    float* out     = (float*)d_out;
    float* partial = (float*)d_ws;   // 1024 floats, fully overwritten by k_fused

    k_fused<<<NBLK, 256, 0, stream>>>(quat, tran, model, view, centers, freev,
                                      occ_other, masks, partial);
    k_final<<<1, 256, 0, stream>>>(partial, out);
}

// Round 4
// 83.032 us; speedup vs baseline: 1.9184x; 1.1350x over previous
//
#include <hip/hip_runtime.h>
#include <math.h>

#define M_PTS   2048
#define N_VOX   65536
#define VPT     4                    // voxels per lane
#define VPB     256                  // voxels per block (64 lanes * VPT)
#define NBLK    (N_VOX / VPB)        // 256 blocks (1 per CU)
#define NWAVES  16                   // 1024-thread blocks
#define CHUNK   (M_PTS / NWAVES)     // 128 points per wave

// ws layout (floats): [0, 1024) per-block partials {pred_sum, fo_sum, mask_occ_sum, mask_sum} x 256

__global__ __launch_bounds__(1024) void k_fused(const float* __restrict__ quat,
                                                const float* __restrict__ tran,
                                                const float* __restrict__ model,
                                                const float* __restrict__ view,
                                                const float* __restrict__ centers,
                                                const float* __restrict__ freev,
                                                const float* __restrict__ occ_other,
                                                const float* __restrict__ masks,
                                                float* __restrict__ partial) {
    __shared__ float4 sp[M_PTS];             // (x,y,z)/RES, h = 0.5*|p/RES|^2  -> 32 KB
    __shared__ float  pmin[NWAVES * VPB];    // [chunk][local voxel]            -> 16 KB
    __shared__ float  sred[16];              // cross-wave sum combine

    const int tid = threadIdx.x;

    // ---- per-block uniform prep: W = inv(view) * quat_matrix (redundant on all threads) ----
    float W[16];
    {
        float q0 = quat[0], q1 = quat[1], q2 = quat[2], q3 = quat[3];
        float nq = q0*q0 + q1*q1 + q2*q2 + q3*q3;
        float s = sqrtf(2.0f / nq);
        q0 *= s; q1 *= s; q2 *= s; q3 *= s;
        float E[16];
        E[0]  = 1.0f - q2*q2 - q3*q3; E[1]  = q1*q2 - q3*q0;        E[2]  = q1*q3 + q2*q0;        E[3]  = tran[0];
        E[4]  = q1*q2 + q3*q0;        E[5]  = 1.0f - q1*q1 - q3*q3; E[6]  = q2*q3 - q1*q0;        E[7]  = tran[1];
        E[8]  = q1*q3 - q2*q0;        E[9]  = q2*q3 + q1*q0;        E[10] = 1.0f - q1*q1 - q2*q2; E[11] = tran[2];
        E[12] = 0.0f; E[13] = 0.0f; E[14] = 0.0f; E[15] = 1.0f;

        float m[16], inv[16];
        #pragma unroll
        for (int i = 0; i < 16; i++) m[i] = view[i];

        inv[0]  =  m[5]*m[10]*m[15] - m[5]*m[11]*m[14] - m[9]*m[6]*m[15] + m[9]*m[7]*m[14] + m[13]*m[6]*m[11] - m[13]*m[7]*m[10];
        inv[4]  = -m[4]*m[10]*m[15] + m[4]*m[11]*m[14] + m[8]*m[6]*m[15] - m[8]*m[7]*m[14] - m[12]*m[6]*m[11] + m[12]*m[7]*m[10];
        inv[8]  =  m[4]*m[9]*m[15]  - m[4]*m[11]*m[13] - m[8]*m[5]*m[15] + m[8]*m[7]*m[13] + m[12]*m[5]*m[11] - m[12]*m[7]*m[9];
        inv[12] = -m[4]*m[9]*m[14]  + m[4]*m[10]*m[13] + m[8]*m[5]*m[14] - m[8]*m[6]*m[13] - m[12]*m[5]*m[10] + m[12]*m[6]*m[9];
        inv[1]  = -m[1]*m[10]*m[15] + m[1]*m[11]*m[14] + m[9]*m[2]*m[15] - m[9]*m[3]*m[14] - m[13]*m[2]*m[11] + m[13]*m[3]*m[10];
        inv[5]  =  m[0]*m[10]*m[15] - m[0]*m[11]*m[14] - m[8]*m[2]*m[15] + m[8]*m[3]*m[14] + m[12]*m[2]*m[11] - m[12]*m[3]*m[10];
        inv[9]  = -m[0]*m[9]*m[15]  + m[0]*m[11]*m[13] + m[8]*m[1]*m[15] - m[8]*m[3]*m[13] - m[12]*m[1]*m[11] + m[12]*m[3]*m[9];
        inv[13] =  m[0]*m[9]*m[14]  - m[0]*m[10]*m[13] - m[8]*m[1]*m[14] + m[8]*m[2]*m[13] + m[12]*m[1]*m[10] - m[12]*m[2]*m[9];
        inv[2]  =  m[1]*m[6]*m[15]  - m[1]*m[7]*m[14]  - m[5]*m[2]*m[15] + m[5]*m[3]*m[14] + m[13]*m[2]*m[7]  - m[13]*m[3]*m[6];
        inv[6]  = -m[0]*m[6]*m[15]  + m[0]*m[7]*m[14]  + m[4]*m[2]*m[15] - m[4]*m[3]*m[14] - m[12]*m[2]*m[7]  + m[12]*m[3]*m[6];
        inv[10] =  m[0]*m[5]*m[15]  - m[0]*m[7]*m[13]  - m[4]*m[1]*m[15] + m[4]*m[3]*m[13] + m[12]*m[1]*m[7]  - m[12]*m[3]*m[5];
        inv[14] = -m[0]*m[5]*m[14]  + m[0]*m[6]*m[13]  + m[4]*m[1]*m[14] - m[4]*m[2]*m[13] - m[12]*m[1]*m[6]  + m[12]*m[2]*m[5];
        inv[3]  = -m[1]*m[6]*m[11]  + m[1]*m[7]*m[10]  + m[5]*m[2]*m[11] - m[5]*m[3]*m[10] - m[9]*m[2]*m[7]   + m[9]*m[3]*m[6];
        inv[7]  =  m[0]*m[6]*m[11]  - m[0]*m[7]*m[10]  - m[4]*m[2]*m[11] + m[4]*m[3]*m[10] + m[8]*m[2]*m[7]   - m[8]*m[3]*m[6];
        inv[11] = -m[0]*m[5]*m[11]  + m[0]*m[7]*m[9]   + m[4]*m[1]*m[11] - m[4]*m[3]*m[9]  - m[8]*m[1]*m[7]   + m[8]*m[3]*m[5];
        inv[15] =  m[0]*m[5]*m[10]  - m[0]*m[6]*m[9]   - m[4]*m[1]*m[10] + m[4]*m[2]*m[9]  + m[8]*m[1]*m[6]   - m[8]*m[2]*m[5];

        float det = m[0]*inv[0] + m[1]*inv[4] + m[2]*inv[8] + m[3]*inv[12];
        float rdet = 1.0f / det;

        #pragma unroll
        for (int r = 0; r < 4; r++) {
            #pragma unroll
            for (int c = 0; c < 4; c++) {
                float a = 0.0f;
                #pragma unroll
                for (int k = 0; k < 4; k++) a += inv[4*r+k] * rdet * E[4*k+c];
                W[4*r+c] = a;
            }
        }
    }

    // ---- transform model points into LDS: p/RES and h = 0.5*|p/RES|^2 (2 pts/thread) ----
    #pragma unroll
    for (int i = tid; i < M_PTS; i += 1024) {
        float x = model[3*i + 0];
        float y = model[3*i + 1];
        float z = model[3*i + 2];
        float X  = W[0]*x + W[1]*y + W[2]*z  + W[3];
        float Y  = W[4]*x + W[5]*y + W[6]*z  + W[7];
        float Z  = W[8]*x + W[9]*y + W[10]*z + W[11];
        float Wd = W[12]*x + W[13]*y + W[14]*z + W[15];
        float rw = 2.0f / Wd;                 // (1/w) * (1/RES)
        float px = X * rw, py = Y * rw, pz = Z * rw;
        float h  = 0.5f * (px*px + py*py + pz*pz);
        sp[i] = make_float4(px, py, pz, h);
    }
    __syncthreads();

    // ---- main: 16 waves x (128-pt chunk); lane covers 4 voxels ----
    const int lane = tid & 63;
    const int wave = tid >> 6;
    const int vbase = blockIdx.x * VPB + lane * VPT;

    float nx[VPT], ny[VPT], nz[VPT], mm[VPT];
    #pragma unroll
    for (int k = 0; k < VPT; k++) {
        int g = vbase + k;
        nx[k] = -centers[3*g + 0] * 2.0f;   // -(c/RES)
        ny[k] = -centers[3*g + 1] * 2.0f;
        nz[k] = -centers[3*g + 2] * 2.0f;
        mm[k] = 1e30f;
    }

    const float4* base = sp + wave * CHUNK;
    #pragma unroll 4
    for (int j = 0; j < CHUNK; ++j) {
        float4 p = base[j];                 // wave-uniform addr -> LDS broadcast
        // t = h - c.p  (d2 = |c|^2 + 2t, monotone)
        #pragma unroll
        for (int k = 0; k < VPT; k++)
            mm[k] = fminf(mm[k], fmaf(nx[k], p.x, fmaf(ny[k], p.y, fmaf(nz[k], p.z, p.w))));
    }
    #pragma unroll
    for (int k = 0; k < VPT; k++)
        pmin[wave * VPB + lane * VPT + k] = mm[k];
    __syncthreads();

    // ---- epilogue: threads 0..255, thread t owns local voxel t ----
    if (tid < VPB) {
        const int g = blockIdx.x * VPB + tid;
        float m = 1e30f;
        #pragma unroll
        for (int c = 0; c < NWAVES; c++)
            m = fminf(m, pmin[c * VPB + tid]);
        float cx = centers[3*g + 0] * 2.0f;
        float cy = centers[3*g + 1] * 2.0f;
        float cz = centers[3*g + 2] * 2.0f;
        float c2 = cx*cx + cy*cy + cz*cz;
        float d2 = fmaf(2.0f, m, c2);
        float dmin = fminf(sqrtf(fmaxf(d2, 0.0f)), 0.25f);   // clamp at RES/2
        float occ  = fmaxf(1.0f - 4.0f * dmin, 0.0f);

        float mk = masks[g];
        float v0 = occ;
        float v1 = (freev[g] + occ_other[g]) * occ;
        float v2 = mk * occ;
        float v3 = mk;

        #pragma unroll
        for (int off = 32; off > 0; off >>= 1) {
            v0 += __shfl_down(v0, off);
            v1 += __shfl_down(v1, off);
            v2 += __shfl_down(v2, off);
            v3 += __shfl_down(v3, off);
        }
        if (lane == 0) {
            sred[wave*4 + 0] = v0;
            sred[wave*4 + 1] = v1;
            sred[wave*4 + 2] = v2;
            sred[wave*4 + 3] = v3;
        }
    }
    __syncthreads();
    if (tid < 4) {
        float s = sred[tid] + sred[4 + tid] + sred[8 + tid] + sred[12 + tid];
        partial[blockIdx.x * 4 + tid] = s;
    }
}

__global__ __launch_bounds__(256) void k_final(const float* __restrict__ partial,
                                               float* __restrict__ out) {
    __shared__ float sred[16];
    const int tid  = threadIdx.x;
    const int lane = tid & 63;
    const int wave = tid >> 6;

    float4 p = ((const float4*)partial)[tid];   // one block's 4 partials per thread
    float v0 = p.x, v1 = p.y, v2 = p.z, v3 = p.w;

    #pragma unroll
    for (int off = 32; off > 0; off >>= 1) {
        v0 += __shfl_down(v0, off);
        v1 += __shfl_down(v1, off);
        v2 += __shfl_down(v2, off);
        v3 += __shfl_down(v3, off);
    }
    if (lane == 0) {
        sred[wave*4 + 0] = v0;
        sred[wave*4 + 1] = v1;
        sred[wave*4 + 2] = v2;
        sred[wave*4 + 3] = v3;
    }
    __syncthreads();
    if (tid == 0) {
        float ps = sred[0] + sred[4] + sred[8]  + sred[12];
        float fo = sred[1] + sred[5] + sred[9]  + sred[13];
        float mo = sred[2] + sred[6] + sred[10] + sred[14];
        float ms = sred[3] + sred[7] + sred[11] + sred[15];
        float t1 = (ps > 0.0f) ? (fo / ps) : 0.0f;
        float t2 = (ms > 0.0f) ? (mo / ms) : 0.0f;
        out[0] = t1 - t2;
    }
}

extern "C" void kernel_launch(void* const* d_in, const int* in_sizes, int n_in,
                              void* d_out, int out_size, void* d_ws, size_t ws_size,
                              hipStream_t stream) {
    const float* quat      = (const float*)d_in[0];
    const float* tran      = (const float*)d_in[1];
    const float* model     = (const float*)d_in[2];
    const float* view      = (const float*)d_in[3];
    const float* centers   = (const float*)d_in[4];
    const float* freev     = (const float*)d_in[5];
    const float* occ_other = (const float*)d_in[6];
    const float* masks     = (const float*)d_in[7];
    float* out     = (float*)d_out;
    float* partial = (float*)d_ws;   // 1024 floats, fully overwritten by k_fused

    k_fused<<<NBLK, 1024, 0, stream>>>(quat, tran, model, view, centers, freev,
                                       occ_other, masks, partial);
    k_final<<<1, 256, 0, stream>>>(partial, out);
}